// Round 6
// baseline (142.302 us; speedup 1.0000x reference)
//
#include <hip/hip_runtime.h>

#define WAVE 64

// ---------------------------------------------------------------------------
// Kernel A: segment start offsets from the sorted batch index, vectorized.
// seg_start[s] = min{ i : batch[i] >= s } for s in [0,B]; seg_start[B] = N.
// One int4 per thread; quad predecessor via __shfl_up (lane 0 loads it).
// Every s in [0,B] written exactly once -> no init needed (poison-immune).
// ---------------------------------------------------------------------------
__global__ void find_starts4_kernel(const int* __restrict__ batch,
                                    int* __restrict__ seg_start,
                                    int N, int B) {
    const int tid  = blockIdx.x * blockDim.x + threadIdx.x;
    const int lane = threadIdx.x & (WAVE - 1);
    const long long i0 = (long long)tid * 4;
    const bool in   = (i0 < N);
    const bool full = (i0 + 3 < N);

    int4 q = make_int4(0, 0, 0, 0);
    if (full) q = ((const int4*)batch)[tid];

    int prevw = __shfl_up(q.w, 1);   // all lanes participate before exit

    if (!in) return;

    int prev;
    if (lane == 0) prev = (i0 == 0) ? -1 : batch[i0 - 1];
    else           prev = prevw;

    if (full) {
        int e[4] = {q.x, q.y, q.z, q.w};
        #pragma unroll
        for (int k = 0; k < 4; ++k) {
            int cur = e[k];
            for (int s = prev + 1; s <= cur; ++s) seg_start[s] = (int)(i0 + k);
            prev = cur;
        }
    } else {
        for (long long j = i0; j < N; ++j) {
            int cur = batch[j];
            for (int s = prev + 1; s <= cur; ++s) seg_start[s] = (int)j;
            prev = cur;
        }
    }

    if (i0 + 4 >= N) {
        for (int s = prev + 1; s <= B; ++s) seg_start[s] = N;
    }
}

// ---------------------------------------------------------------------------
// Kernel B: grid sized to device wave capacity; each wave owns a CONTIGUOUS
// pair of segments (2w, 2w+1) -> one linear ~610-row stream per wave, half
// the wave count, three bounds loads. Per segment: coalesced float4
// accumulation (2x unrolled, dual accumulators), wave tree-reduction, lane 0
// runs the fused 5->5->1 MLP and writes out[seg].
// ---------------------------------------------------------------------------
__global__ void __launch_bounds__(256)
seg_mean_mlp_kernel(const float4* __restrict__ x,
                    const int* __restrict__ seg_start,
                    const float* __restrict__ u,
                    const float* __restrict__ W1,   // [5,5] row-major
                    const float* __restrict__ b1,   // [5]
                    const float* __restrict__ W2,   // [5]
                    const float* __restrict__ b2,   // [1]
                    float* __restrict__ out, int B) {
    const int wave_id = (blockIdx.x * blockDim.x + threadIdx.x) / WAVE;
    const int lane    = threadIdx.x & (WAVE - 1);

    const int s0 = wave_id * 2;
    if (s0 >= B) return;

    const int bound0 = seg_start[s0];
    const int bound1 = seg_start[s0 + 1];
    const int bound2 = (s0 + 1 < B) ? seg_start[s0 + 2] : bound1;

    #pragma unroll
    for (int pair = 0; pair < 2; ++pair) {
        const int seg   = s0 + pair;
        if (seg >= B) break;
        const int start = pair ? bound1 : bound0;
        const int end   = pair ? bound2 : bound1;

        float4 a0 = make_float4(0.f, 0.f, 0.f, 0.f);
        float4 a1 = make_float4(0.f, 0.f, 0.f, 0.f);

        int i = start + lane;
        for (; i + WAVE < end; i += 2 * WAVE) {
            float4 v0 = x[i];
            float4 v1 = x[i + WAVE];
            a0.x += v0.x; a0.y += v0.y; a0.z += v0.z; a0.w += v0.w;
            a1.x += v1.x; a1.y += v1.y; a1.z += v1.z; a1.w += v1.w;
        }
        if (i < end) {
            float4 v = x[i];
            a0.x += v.x; a0.y += v.y; a0.z += v.z; a0.w += v.w;
        }
        a0.x += a1.x; a0.y += a1.y; a0.z += a1.z; a0.w += a1.w;

        #pragma unroll
        for (int off = 32; off > 0; off >>= 1) {
            a0.x += __shfl_down(a0.x, off);
            a0.y += __shfl_down(a0.y, off);
            a0.z += __shfl_down(a0.z, off);
            a0.w += __shfl_down(a0.w, off);
        }

        if (lane == 0) {
            const int cnt = end - start;
            const float inv = (cnt > 0) ? (1.0f / (float)cnt) : 0.0f;

            float h[5];
            h[0] = u[seg];
            h[1] = a0.x * inv;
            h[2] = a0.y * inv;
            h[3] = a0.z * inv;
            h[4] = a0.w * inv;

            float o = b2[0];
            #pragma unroll
            for (int j = 0; j < 5; ++j) {
                float s = b1[j];
                #pragma unroll
                for (int i2 = 0; i2 < 5; ++i2) s += h[i2] * W1[i2 * 5 + j];
                s = (s > 0.0f) ? s : 0.1f * s;   // leaky_relu, slope 0.1
                o += s * W2[j];
            }
            out[seg] = o;
        }
    }
}

extern "C" void kernel_launch(void* const* d_in, const int* in_sizes, int n_in,
                              void* d_out, int out_size, void* d_ws, size_t ws_size,
                              hipStream_t stream) {
    const float* x     = (const float*)d_in[0];  // [N,4]
    const int*   batch = (const int*)  d_in[1];  // [N]
    const float* u     = (const float*)d_in[2];  // [B,1]
    const float* W1    = (const float*)d_in[3];  // [5,5]
    const float* b1    = (const float*)d_in[4];  // [5]
    const float* W2    = (const float*)d_in[5];  // [5,1]
    const float* b2    = (const float*)d_in[6];  // [1]
    float* out = (float*)d_out;

    const int N = in_sizes[0] / 4;
    const int B = out_size;                      // output is [B,1]

    int* seg_start = (int*)d_ws;                 // [B+1] ints, fully rewritten

    const int quads = (N + 3) / 4;
    find_starts4_kernel<<<(quads + 255) / 256, 256, 0, stream>>>(batch, seg_start, N, B);

    // one wave per 2 contiguous segments: B/2 waves = B*32 threads
    const int threads = 256;
    const int waves   = (B + 1) / 2;
    const int blocks  = (int)(((long long)waves * WAVE + threads - 1) / threads);
    seg_mean_mlp_kernel<<<blocks, threads, 0, stream>>>(
        (const float4*)x, seg_start, u, W1, b1, W2, b2, out, B);
}